// Round 11
// baseline (269.174 us; speedup 1.0000x reference)
//
#include <hip/hip_runtime.h>
#include <hip/hip_bf16.h>
#include <cstdint>
#include <cstddef>

typedef float f32x16 __attribute__((ext_vector_type(16)));
typedef float f32x4  __attribute__((ext_vector_type(4)));
typedef float f32x2  __attribute__((ext_vector_type(2)));
typedef float f32x4v __attribute__((ext_vector_type(4)));
typedef short short8 __attribute__((ext_vector_type(8)));
typedef unsigned short us4 __attribute__((ext_vector_type(4)));
typedef unsigned int u32;
typedef unsigned short u16;

#define MFMA32(a,b,c) __builtin_amdgcn_mfma_f32_32x32x16_bf16(a,b,c,0,0,0)
#define MFMA16(a,b,c) __builtin_amdgcn_mfma_f32_16x16x32_bf16(a,b,c,0,0,0)

#define HN 16
#define NQL 2048
#define NKL 2048
#define DM 1024

// 0.125 (1/sqrt(64)) * log2(e), folded into Q at projection time.
#define QSCALE 0.18033688011112042f

static __device__ __forceinline__ u16 f2bf(float f){
  union{float f;u32 u;}x; x.f=f; u32 u=x.u;
  return (u16)((u + 0x7fffu + ((u>>16)&1u))>>16);
}

#define AS1q __attribute__((address_space(1)))
#define AS3q __attribute__((address_space(3)))
static __device__ __forceinline__ void gload16(const void* g, void* l){
  __builtin_amdgcn_global_load_lds((const AS1q u32*)g, (AS3q u32*)l, 16, 0, 0);
}
// W-stream: NT (evict-first) — best measured policy (R6: -13us; R7 SC1: null).
static __device__ __forceinline__ void gload16nt(const void* g, void* l){
  __builtin_amdgcn_global_load_lds((const AS1q u32*)g, (AS3q u32*)l, 16, 0, 2);
}

// ---------------- ws layout (bytes) ----------------
#define OFF_ABF   (size_t)(0)          // 3 * 4096*1024 bf16 = 25165824
#define OFF_BTQKV (size_t)(25165824)   // 3072*1024 bf16 = 6291456
#define OFF_BTO   (size_t)(31457280)   // 1024*1024 bf16 = 2097152
#define OFF_QP    (size_t)(33554432)   // [B,H,2048,64] bf16 = 8388608
#define OFF_KP    (size_t)(41943040)
#define OFF_VT    (size_t)(58720256)   // [B,H,64,2048] bf16
#define OFF_AOUT  (size_t)(67108864)   // [B,2048,1024] bf16
// total 75497472 bytes (72 MB)

// ---------------- fused cast (q/k/v -> bf16) + weight transpose-cast ----------------
// blocks [0,12288): cast3 path. blocks [12288,16384): twcast path.
__global__ void castw_kernel(const float* __restrict__ q, const float* __restrict__ k,
                             const float* __restrict__ v, u16* __restrict__ dst,
                             const float* __restrict__ wq, const float* __restrict__ wk,
                             const float* __restrict__ wv, const float* __restrict__ wo,
                             u16* __restrict__ btqkv, u16* __restrict__ bto){
  __shared__ float tile[32][33];
  int bx = blockIdx.x;
  if (bx < 12288){
    int i = bx*256 + threadIdx.x;              // 3*2^20 float4 units
    const float* src = (i < 1048576) ? q : (i < 2097152 ? k : v);
    int j = i & 1048575;
    f32x4v val = __builtin_nontemporal_load((const f32x4v*)src + j);
    ushort4 o; o.x=f2bf(val.x); o.y=f2bf(val.y); o.z=f2bf(val.z); o.w=f2bf(val.w);
    ((ushort4*)dst)[i] = o;
  } else {
    int w = bx - 12288;                        // [0,4096)
    int which = w >> 10;
    int rem = w & 1023;
    int n0 = (rem & 31)*32, k0 = (rem >> 5)*32;
    const float* src = which==0?wq:which==1?wk:which==2?wv:wo;
    u16* dstw = which<3 ? btqkv + (size_t)which*1024*1024 : bto;
    int tx = threadIdx.x & 31, ty = threadIdx.x >> 5;
    #pragma unroll
    for (int j=0;j<4;j++)
      tile[ty+8*j][tx] = __builtin_nontemporal_load(&src[(size_t)(k0+ty+8*j)*1024 + n0+tx]);
    __syncthreads();
    #pragma unroll
    for (int j=0;j<4;j++) dstw[(size_t)(n0+ty+8*j)*1024 + k0+tx] = f2bf(tile[tx][ty+8*j]);
  }
}

// ---------------- GEMM0: QKV projection (A 4096x1024 * Bt^T), scatter ----------------
// which=0 -> qp (bias+QSCALE), which=1 -> kp (bias), which=2 -> vt TRANSPOSED (bias)
// XCD swizzle (T1, proven -2.6us R10): 768 = 8 XCDs x 96.
__global__ __launch_bounds__(256) void gemm0_kernel(
    const u16* __restrict__ Abase, const u16* __restrict__ Bt,
    const float* __restrict__ b0, const float* __restrict__ b1, const float* __restrict__ b2,
    u16* __restrict__ qp, u16* __restrict__ kp, u16* __restrict__ vt)
{
  __shared__ u16 lds[2*128*64];   // A tile [128][64], B tile [128][64], 32 KB
  const int t = threadIdx.x;
  const int lane = t & 63, w = t >> 6;
  const int l15 = lane & 15, l4 = lane >> 4;
  const int lin = blockIdx.y*24 + blockIdx.x;     // [0,768)
  const int swz = (lin & 7)*96 + (lin >> 3);      // bijective: 768 = 8*96
  const int n0 = (swz % 24)*128, m0 = (swz / 24)*128;
  const int which = n0 >> 10;
  const u16* A = Abase + (size_t)which*4096*1024;
  const int wr = w >> 1, wc = w & 1;

  f32x4 acc[4][4];
  #pragma unroll
  for (int i=0;i<4;i++)
    #pragma unroll
    for (int j=0;j<4;j++){ acc[i][j][0]=0.f; acc[i][j][1]=0.f; acc[i][j][2]=0.f; acc[i][j][3]=0.f; }

  for (int kk=0; kk<16; kk++){
    #pragma unroll
    for (int i=0;i<4;i++){
      int o = i*4096 + w*1024 + lane*16;
      int row = o >> 7, c16 = (o >> 4) & 7;
      int c16s = c16 ^ (row & 7);
      gload16(A + ((size_t)(m0+row)*1024 + kk*64 + c16s*8), (char*)lds + (i*4096 + w*1024));
    }
    #pragma unroll
    for (int i=0;i<4;i++){
      int o = i*4096 + w*1024 + lane*16;
      int row = o >> 7, c16 = (o >> 4) & 7;
      int c16s = c16 ^ (row & 7);
      gload16(Bt + ((size_t)(n0+row)*1024 + kk*64 + c16s*8), (char*)lds + 16384 + (i*4096 + w*1024));
    }
    __syncthreads();

    short8 af[4][2], bf[4][2];
    #pragma unroll
    for (int mr=0;mr<4;mr++)
      #pragma unroll
      for (int ks=0;ks<2;ks++){
        int row = wr*64 + mr*16 + l15;
        int c16 = ks*4 + l4;
        af[mr][ks] = *(const short8*)((const char*)lds + row*128 + ((c16 ^ (row&7))*16));
      }
    #pragma unroll
    for (int nc=0;nc<4;nc++)
      #pragma unroll
      for (int ks=0;ks<2;ks++){
        int row = wc*64 + nc*16 + l15;
        int c16 = ks*4 + l4;
        bf[nc][ks] = *(const short8*)((const char*)lds + 16384 + row*128 + ((c16 ^ (row&7))*16));
      }
    #pragma unroll
    for (int ks=0;ks<2;ks++)
      #pragma unroll
      for (int mr=0;mr<4;mr++)
        #pragma unroll
        for (int nc=0;nc<4;nc++)
          acc[mr][nc] = MFMA16(af[mr][ks], bf[nc][ks], acc[mr][nc]);
    __syncthreads();
  }

  if (which < 2){
    const float* bias = which==0?b0:b1;
    u16* dst = which==0?qp:kp;
    const float sc = (which==0) ? QSCALE : 1.0f;
    #pragma unroll
    for (int mr=0;mr<4;mr++)
      #pragma unroll
      for (int nc=0;nc<4;nc++)
        #pragma unroll
        for (int r=0;r<4;r++){
          int grow = m0 + wr*64 + mr*16 + l4*4 + r;
          int gcol = n0 + wc*64 + nc*16 + l15;
          int c1024 = gcol & 1023;
          float val = (acc[mr][nc][r] + bias[c1024]) * sc;
          int bsel = grow >> 11, nn = grow & 2047;
          int hh = c1024 >> 6, dd = gcol & 63;
          dst[((size_t)(bsel*HN+hh)*NQL + nn)*64 + dd] = f2bf(val);
        }
  } else {
    // V: write transposed directly -> vt[b*16+h][d][n], 4 consecutive n per lane
    #pragma unroll
    for (int mr=0;mr<4;mr++)
      #pragma unroll
      for (int nc=0;nc<4;nc++){
        int grow0 = m0 + wr*64 + mr*16 + l4*4;
        int gcol = n0 + wc*64 + nc*16 + l15;
        int c1024 = gcol & 1023;
        int bsel = grow0 >> 11, nn = grow0 & 2047;
        int hh = c1024 >> 6, dd = c1024 & 63;
        float bv_ = b2[c1024];
        us4 pk;
        pk.x = f2bf(acc[mr][nc][0] + bv_);
        pk.y = f2bf(acc[mr][nc][1] + bv_);
        pk.z = f2bf(acc[mr][nc][2] + bv_);
        pk.w = f2bf(acc[mr][nc][3] + bv_);
        *(us4*)(vt + ((size_t)(bsel*HN+hh)*64 + dd)*NKL + nn) = pk;
      }
  }
}

// ---------------- GEMM1: out = aout(4096x1024 bf16) @ bto^T + bo, f32 out ----------------
// XCD swizzle: 512 blocks = 8 x 64.
__global__ __launch_bounds__(256) void gemm1_kernel(
    const u16* __restrict__ A, const u16* __restrict__ Bt,
    const float* __restrict__ bo, float* __restrict__ out)
{
  __shared__ u16 lds[(64+128)*64];   // A [64][64] @0, B [128][64] @8KB; 24 KB
  const int t = threadIdx.x;
  const int lane = t & 63, w = t >> 6;
  const int l15 = lane & 15, l4 = lane >> 4;
  const int lin = blockIdx.y*8 + blockIdx.x;      // [0,512)
  const int swz = (lin & 7)*64 + (lin >> 3);      // bijective: 512 = 8*64
  const int n0 = (swz & 7)*128, m0 = (swz >> 3)*64;
  const int wr = w >> 1, wc = w & 1;

  f32x4 acc[2][4];
  #pragma unroll
  for (int i=0;i<2;i++)
    #pragma unroll
    for (int j=0;j<4;j++){ acc[i][j][0]=0.f; acc[i][j][1]=0.f; acc[i][j][2]=0.f; acc[i][j][3]=0.f; }

  for (int kk=0; kk<16; kk++){
    #pragma unroll
    for (int i=0;i<2;i++){
      int o = i*4096 + w*1024 + lane*16;
      int row = o >> 7, c16 = (o >> 4) & 7;
      int c16s = c16 ^ (row & 7);
      gload16(A + ((size_t)(m0+row)*1024 + kk*64 + c16s*8), (char*)lds + (i*4096 + w*1024));
    }
    #pragma unroll
    for (int i=0;i<4;i++){
      int o = i*4096 + w*1024 + lane*16;
      int row = o >> 7, c16 = (o >> 4) & 7;
      int c16s = c16 ^ (row & 7);
      gload16(Bt + ((size_t)(n0+row)*1024 + kk*64 + c16s*8), (char*)lds + 8192 + (i*4096 + w*1024));
    }
    __syncthreads();

    short8 af[2][2], bf[4][2];
    #pragma unroll
    for (int mr=0;mr<2;mr++)
      #pragma unroll
      for (int ks=0;ks<2;ks++){
        int row = wr*32 + mr*16 + l15;
        int c16 = ks*4 + l4;
        af[mr][ks] = *(const short8*)((const char*)lds + row*128 + ((c16 ^ (row&7))*16));
      }
    #pragma unroll
    for (int nc=0;nc<4;nc++)
      #pragma unroll
      for (int ks=0;ks<2;ks++){
        int row = wc*64 + nc*16 + l15;
        int c16 = ks*4 + l4;
        bf[nc][ks] = *(const short8*)((const char*)lds + 8192 + row*128 + ((c16 ^ (row&7))*16));
      }
    #pragma unroll
    for (int ks=0;ks<2;ks++)
      #pragma unroll
      for (int mr=0;mr<2;mr++)
        #pragma unroll
        for (int nc=0;nc<4;nc++)
          acc[mr][nc] = MFMA16(af[mr][ks], bf[nc][ks], acc[mr][nc]);
    __syncthreads();
  }

  #pragma unroll
  for (int mr=0;mr<2;mr++)
    #pragma unroll
    for (int nc=0;nc<4;nc++)
      #pragma unroll
      for (int r=0;r<4;r++){
        int grow = m0 + wr*32 + mr*16 + l4*4 + r;
        int gcol = n0 + wc*64 + nc*16 + l15;
        out[(size_t)grow*1024 + gcol] = acc[mr][nc][r] + bo[gcol];
      }
}

// ---------------- flash attention v4 (R8-proven): 8-wave blocks, W LDS slab ----------------
__global__ __launch_bounds__(512) void attn_kernel(
  const u16* __restrict__ qp, const u16* __restrict__ kp, const u16* __restrict__ vt,
  const float* __restrict__ wts, u16* __restrict__ aout)
{
  __shared__ __align__(16) char lds[131072];
  char* kl = lds;
  char* vl = lds + 16384;
  const int tid = threadIdx.x;
  const int lane = tid & 63, wid = tid >> 6;
  const int lo = lane & 31, hi = lane >> 5;
  char* wl = lds + 32768 + wid*8192;
  char* pl = lds + 98304 + wid*4096;

  const int g = blockIdx.x;             // [0,256)
  const int j = g >> 3;                 // [0,32)
  const int bh = (g & 7)*4 + (j >> 3);  // 4 heads per XCD
  const int qblk = j & 7;               // 8 q-blocks of 256 rows
  const int b = bh >> 4;
  const int q0 = qblk*256 + wid*32;

  const u16* qb = qp + ((size_t)bh*NQL + q0)*64;
  const u16* kb = kp + (size_t)bh*NKL*64;
  const u16* vb = vt + (size_t)bh*64*NKL;
  const float* wb = wts + ((size_t)bh*NQL + q0)*(size_t)NKL;

  short8 qf[4];
  #pragma unroll
  for (int ks=0;ks<4;ks++)
    qf[ks] = *(const short8*)(qb + (size_t)lo*64 + ks*16 + hi*8);

  f32x16 o0, o1;
  float ls[16];
  #pragma unroll
  for (int r=0;r<16;r++){ o0[r]=0.f; o1[r]=0.f; ls[r]=0.f; }

  const int krow = tid >> 3, ksl = tid & 7;
  const int le16 = lane & 15, ld16 = lane >> 4;

  {
    gload16(kb + (size_t)krow*64 + (ksl ^ ((krow>>1)&7))*8, kl + tid*16);
    gload16(vb + (size_t)krow*NKL + (ksl ^ (krow&7))*8,     vl + tid*16);
    #pragma unroll
    for (int i=0;i<8;i++){
      int q = 4*i + ld16;
      gload16nt(wb + (size_t)q*NKL + le16*4, wl + i*1024);
    }
  }
  __syncthreads();

  for (int kt=0; kt<32; kt++){
    const int cur = (kt&1)*8192;
    const int nxt = cur ^ 8192;
    const int kb0 = kt*64;

    if (kt < 31){
      int kb1 = kb0 + 64;
      gload16(kb + (size_t)(kb1+krow)*64 + (ksl ^ ((krow>>1)&7))*8, kl + nxt + tid*16);
      gload16(vb + (size_t)krow*NKL + kb1 + (ksl ^ (krow&7))*8,     vl + nxt + tid*16);
    }

    f32x2 wp[16];
    #pragma unroll
    for (int r=0;r<16;r++){
      int qr = (r&3) + 8*(r>>2) + 4*hi;
      wp[r] = *(const f32x2*)(wl + qr*256 + lo*8);
    }
    short8 kf0[4], kf1[4];
    #pragma unroll
    for (int ks=0;ks<4;ks++){
      int slot = (ks*2 + hi) ^ (lo&7);
      kf0[ks] = *(const short8*)(kl + cur + (2*lo)*128 + slot*16);
      kf1[ks] = *(const short8*)(kl + cur + (2*lo)*128 + 128 + slot*16);
    }
    asm volatile("s_waitcnt lgkmcnt(0)" ::: "memory");
    __builtin_amdgcn_sched_barrier(0);

    if (kt < 31){
      int kb1 = kb0 + 64;
      #pragma unroll
      for (int i=0;i<8;i++){
        int q = 4*i + ld16;
        gload16nt(wb + (size_t)q*NKL + kb1 + le16*4, wl + i*1024);
      }
    }

    f32x16 s0, s1;
    #pragma unroll
    for (int r=0;r<16;r++){ s0[r]=0.f; s1[r]=0.f; }
    #pragma unroll
    for (int ks=0;ks<4;ks++){
      s0 = MFMA32(qf[ks], kf0[ks], s0);
      s1 = MFMA32(qf[ks], kf1[ks], s1);
    }

    short8 vf0[4], vf1[4];
    #pragma unroll
    for (int t=0;t<4;t++){
      int slot = (t*2 + hi) ^ (lo&7);
      vf0[t] = *(const short8*)(vl + cur + lo*128 + slot*16);
      vf1[t] = *(const short8*)(vl + cur + (32+lo)*128 + slot*16);
    }

    #pragma unroll
    for (int r=0;r<16;r++){
      float p0 = exp2f(s0[r] * wp[r].x);
      float p1 = exp2f(s1[r] * wp[r].y);
      ls[r] += p0 + p1;
      u32 pk;
      asm("v_cvt_pk_bf16_f32 %0, %1, %2" : "=v"(pk) : "v"(p0), "v"(p1));
      int row = (r&3) + 8*(r>>2) + 4*hi;
      *(u32*)(pl + row*128 + ((lo*4) ^ ((row&7)<<4))) = pk;
    }
    asm volatile("s_waitcnt lgkmcnt(0)" ::: "memory");
    short8 pf[4];
    #pragma unroll
    for (int t=0;t<4;t++)
      pf[t] = *(const short8*)(pl + lo*128 + ((t*32 + hi*16) ^ ((lo&7)<<4)));
    #pragma unroll
    for (int t=0;t<4;t++){
      o0 = MFMA32(pf[t], vf0[t], o0);
      o1 = MFMA32(pf[t], vf1[t], o1);
    }
    __syncthreads();
  }

  u16* ob = aout + ((size_t)b*NQL + q0)*DM + (bh & 15)*64;
  #pragma unroll
  for (int r=0;r<16;r++){
    float L = ls[r];
    L += __shfl_xor(L,1); L += __shfl_xor(L,2); L += __shfl_xor(L,4);
    L += __shfl_xor(L,8); L += __shfl_xor(L,16);
    float inv = 1.0f / L;
    int q = (r&3) + 8*(r>>2) + 4*hi;
    ob[(size_t)q*DM + lo]      = f2bf(o0[r]*inv);
    ob[(size_t)q*DM + 32 + lo] = f2bf(o1[r]*inv);
  }
}

// ---------------- launcher ----------------
extern "C" void kernel_launch(void* const* d_in, const int* in_sizes, int n_in,
                              void* d_out, int out_size, void* d_ws, size_t ws_size,
                              hipStream_t stream){
  const float* queries = (const float*)d_in[0];
  const float* keys    = (const float*)d_in[1];
  const float* values  = (const float*)d_in[2];
  const float* attw    = (const float*)d_in[3];
  const float* Wq = (const float*)d_in[4];
  const float* bq = (const float*)d_in[5];
  const float* Wk = (const float*)d_in[6];
  const float* bk = (const float*)d_in[7];
  const float* Wv = (const float*)d_in[8];
  const float* bv = (const float*)d_in[9];
  const float* Wo = (const float*)d_in[10];
  const float* bo = (const float*)d_in[11];
  char* ws = (char*)d_ws;
  u16* abf   = (u16*)(ws + OFF_ABF);
  u16* btqkv = (u16*)(ws + OFF_BTQKV);
  u16* bto   = (u16*)(ws + OFF_BTO);
  u16* qp    = (u16*)(ws + OFF_QP);
  u16* kp    = (u16*)(ws + OFF_KP);
  u16* vt    = (u16*)(ws + OFF_VT);
  u16* aout  = (u16*)(ws + OFF_AOUT);
  float* out = (float*)d_out;

  castw_kernel<<<16384, 256, 0, stream>>>(queries, keys, values, abf,
                                          Wq, Wk, Wv, Wo, btqkv, bto);
  // MEASUREMENT: gemm0/gemm1 launched TWICE (idempotent).
  // (gemm0+gemm1) ~= dur_this_round - (dur_R10 - castw_savings). Remove next round.
  gemm0_kernel<<<dim3(24,32), 256, 0, stream>>>(abf, btqkv, bq,bk,bv, qp,kp,vt);
  gemm0_kernel<<<dim3(24,32), 256, 0, stream>>>(abf, btqkv, bq,bk,bv, qp,kp,vt);
  attn_kernel<<<256, 512, 0, stream>>>(qp, kp, vt, attw, aout);
  gemm1_kernel<<<dim3(8,64), 256, 0, stream>>>(aout, bto, bo, out);
  gemm1_kernel<<<dim3(8,64), 256, 0, stream>>>(aout, bto, bo, out);
}

// Round 12
// 210.360 us; speedup vs baseline: 1.2796x; 1.2796x over previous
//
#include <hip/hip_runtime.h>
#include <hip/hip_bf16.h>
#include <cstdint>
#include <cstddef>

typedef float f32x16 __attribute__((ext_vector_type(16)));
typedef float f32x4  __attribute__((ext_vector_type(4)));
typedef float f32x2  __attribute__((ext_vector_type(2)));
typedef float f32x4v __attribute__((ext_vector_type(4)));
typedef short short8 __attribute__((ext_vector_type(8)));
typedef unsigned short us4 __attribute__((ext_vector_type(4)));
typedef unsigned short us8 __attribute__((ext_vector_type(8)));
typedef unsigned int u32;
typedef unsigned short u16;

#define MFMA32(a,b,c) __builtin_amdgcn_mfma_f32_32x32x16_bf16(a,b,c,0,0,0)
#define MFMA16(a,b,c) __builtin_amdgcn_mfma_f32_16x16x32_bf16(a,b,c,0,0,0)

#define HN 16
#define NQL 2048
#define NKL 2048
#define DM 1024

// 0.125 (1/sqrt(64)) * log2(e), folded into Q at projection time.
#define QSCALE 0.18033688011112042f

static __device__ __forceinline__ u16 f2bf(float f){
  union{float f;u32 u;}x; x.f=f; u32 u=x.u;
  return (u16)((u + 0x7fffu + ((u>>16)&1u))>>16);
}

#define AS1q __attribute__((address_space(1)))
#define AS3q __attribute__((address_space(3)))
static __device__ __forceinline__ void gload16(const void* g, void* l){
  __builtin_amdgcn_global_load_lds((const AS1q u32*)g, (AS3q u32*)l, 16, 0, 0);
}
// W-stream: NT (evict-first) — best measured policy (R6: -13us; R7 SC1: null).
static __device__ __forceinline__ void gload16nt(const void* g, void* l){
  __builtin_amdgcn_global_load_lds((const AS1q u32*)g, (AS3q u32*)l, 16, 0, 2);
}

// ---------------- ws layout (bytes) ----------------
#define OFF_ABF   (size_t)(0)          // 3 * 4096*1024 bf16 = 25165824
#define OFF_BTQKV (size_t)(25165824)   // 3072*1024 bf16 = 6291456
#define OFF_BTO   (size_t)(31457280)   // 1024*1024 bf16 = 2097152
#define OFF_QP    (size_t)(33554432)   // [B,H,2048,64] bf16 = 8388608
#define OFF_KP    (size_t)(41943040)
#define OFF_VT    (size_t)(58720256)   // [B,H,64,2048] bf16
#define OFF_AOUT  (size_t)(67108864)   // [B,2048,1024] bf16
// total 75497472 bytes (72 MB)

// ---------------- fused cast (q/k/v -> bf16) + weight transpose-cast ----------------
__global__ void castw_kernel(const float* __restrict__ q, const float* __restrict__ k,
                             const float* __restrict__ v, u16* __restrict__ dst,
                             const float* __restrict__ wq, const float* __restrict__ wk,
                             const float* __restrict__ wv, const float* __restrict__ wo,
                             u16* __restrict__ btqkv, u16* __restrict__ bto){
  __shared__ float tile[32][33];
  int bx = blockIdx.x;
  if (bx < 12288){
    int i = bx*256 + threadIdx.x;              // 3*2^20 float4 units
    const float* src = (i < 1048576) ? q : (i < 2097152 ? k : v);
    int j = i & 1048575;
    f32x4v val = __builtin_nontemporal_load((const f32x4v*)src + j);
    ushort4 o; o.x=f2bf(val.x); o.y=f2bf(val.y); o.z=f2bf(val.z); o.w=f2bf(val.w);
    ((ushort4*)dst)[i] = o;
  } else {
    int w = bx - 12288;                        // [0,4096)
    int which = w >> 10;
    int rem = w & 1023;
    int n0 = (rem & 31)*32, k0 = (rem >> 5)*32;
    const float* src = which==0?wq:which==1?wk:which==2?wv:wo;
    u16* dstw = which<3 ? btqkv + (size_t)which*1024*1024 : bto;
    int tx = threadIdx.x & 31, ty = threadIdx.x >> 5;
    #pragma unroll
    for (int j=0;j<4;j++)
      tile[ty+8*j][tx] = __builtin_nontemporal_load(&src[(size_t)(k0+ty+8*j)*1024 + n0+tx]);
    __syncthreads();
    #pragma unroll
    for (int j=0;j<4;j++) dstw[(size_t)(n0+ty+8*j)*1024 + k0+tx] = f2bf(tile[tx][ty+8*j]);
  }
}

// ---------------- GEMM0: QKV projection (A 4096x1024 * Bt^T), scatter ----------------
// which=0 -> qp (bias+QSCALE), which=1 -> kp (bias), which=2 -> vt TRANSPOSED (bias)
// XCD swizzle (T1, proven -2.6us R10): 768 = 8 XCDs x 96.
// qp/kp epilogue: C staged through LDS (swizzled) -> fully-coalesced 16B stores.
__global__ __launch_bounds__(256) void gemm0_kernel(
    const u16* __restrict__ Abase, const u16* __restrict__ Bt,
    const float* __restrict__ b0, const float* __restrict__ b1, const float* __restrict__ b2,
    u16* __restrict__ qp, u16* __restrict__ kp, u16* __restrict__ vt)
{
  __shared__ u16 lds[2*128*64];   // staging; reused as C tile [128][128] bf16 in epilogue
  const int t = threadIdx.x;
  const int lane = t & 63, w = t >> 6;
  const int l15 = lane & 15, l4 = lane >> 4;
  const int lin = blockIdx.y*24 + blockIdx.x;     // [0,768)
  const int swz = (lin & 7)*96 + (lin >> 3);      // bijective: 768 = 8*96
  const int n0 = (swz % 24)*128, m0 = (swz / 24)*128;
  const int which = n0 >> 10;
  const u16* A = Abase + (size_t)which*4096*1024;
  const int wr = w >> 1, wc = w & 1;

  f32x4 acc[4][4];
  #pragma unroll
  for (int i=0;i<4;i++)
    #pragma unroll
    for (int j=0;j<4;j++){ acc[i][j][0]=0.f; acc[i][j][1]=0.f; acc[i][j][2]=0.f; acc[i][j][3]=0.f; }

  for (int kk=0; kk<16; kk++){
    #pragma unroll
    for (int i=0;i<4;i++){
      int o = i*4096 + w*1024 + lane*16;
      int row = o >> 7, c16 = (o >> 4) & 7;
      int c16s = c16 ^ (row & 7);
      gload16(A + ((size_t)(m0+row)*1024 + kk*64 + c16s*8), (char*)lds + (i*4096 + w*1024));
    }
    #pragma unroll
    for (int i=0;i<4;i++){
      int o = i*4096 + w*1024 + lane*16;
      int row = o >> 7, c16 = (o >> 4) & 7;
      int c16s = c16 ^ (row & 7);
      gload16(Bt + ((size_t)(n0+row)*1024 + kk*64 + c16s*8), (char*)lds + 16384 + (i*4096 + w*1024));
    }
    __syncthreads();

    short8 af[4][2], bf[4][2];
    #pragma unroll
    for (int mr=0;mr<4;mr++)
      #pragma unroll
      for (int ks=0;ks<2;ks++){
        int row = wr*64 + mr*16 + l15;
        int c16 = ks*4 + l4;
        af[mr][ks] = *(const short8*)((const char*)lds + row*128 + ((c16 ^ (row&7))*16));
      }
    #pragma unroll
    for (int nc=0;nc<4;nc++)
      #pragma unroll
      for (int ks=0;ks<2;ks++){
        int row = wc*64 + nc*16 + l15;
        int c16 = ks*4 + l4;
        bf[nc][ks] = *(const short8*)((const char*)lds + 16384 + row*128 + ((c16 ^ (row&7))*16));
      }
    #pragma unroll
    for (int ks=0;ks<2;ks++)
      #pragma unroll
      for (int mr=0;mr<4;mr++)
        #pragma unroll
        for (int nc=0;nc<4;nc++)
          acc[mr][nc] = MFMA16(af[mr][ks], bf[nc][ks], acc[mr][nc]);
    __syncthreads();
  }

  if (which < 2){
    const float* bias = which==0?b0:b1;
    u16* dst = which==0?qp:kp;
    const float sc = (which==0) ? QSCALE : 1.0f;
    // 1) C -> LDS (bf16, XOR-swizzled rows of 256B)
    #pragma unroll
    for (int mr=0;mr<4;mr++)
      #pragma unroll
      for (int nc=0;nc<4;nc++)
        #pragma unroll
        for (int r=0;r<4;r++){
          int row = wr*64 + mr*16 + l4*4 + r;
          int col = wc*64 + nc*16 + l15;
          float val = (acc[mr][nc][r] + bias[(n0+col)&1023]) * sc;
          *(u16*)((char*)lds + ((row*256 + col*2) ^ ((row&7)<<4))) = f2bf(val);
        }
    __syncthreads();
    // 2) coalesced stores: per col-half (64 d = one head slice), dst is a
    //    contiguous 16KB run (tokens m0..m0+127 x 128B). 4 passes x 16B/thread.
    #pragma unroll
    for (int half=0; half<2; half++){
      int hh = ((n0 + half*64) & 1023) >> 6;
      int bsel = m0 >> 11;
      int nn0 = m0 & 2047;
      u16* dbase = dst + ((size_t)(bsel*HN + hh)*NQL + nn0)*64;
      #pragma unroll
      for (int p=0;p<4;p++){
        int o = p*4096 + t*16;          // byte offset in the 16KB half-image
        int row = o >> 7;               // token-local
        int cb  = (o & 127) + half*128; // byte col within the 256B LDS row
        us8 v = *(const us8*)((const char*)lds + ((row*256 + cb) ^ ((row&7)<<4)));
        *(us8*)((char*)dbase + o) = v;
      }
    }
  } else {
    // V: write transposed directly -> vt[b*16+h][d][n], 4 consecutive n per lane
    #pragma unroll
    for (int mr=0;mr<4;mr++)
      #pragma unroll
      for (int nc=0;nc<4;nc++){
        int grow0 = m0 + wr*64 + mr*16 + l4*4;
        int gcol = n0 + wc*64 + nc*16 + l15;
        int c1024 = gcol & 1023;
        int bsel = grow0 >> 11, nn = grow0 & 2047;
        int hh = c1024 >> 6, dd = c1024 & 63;
        float bv_ = b2[c1024];
        us4 pk;
        pk.x = f2bf(acc[mr][nc][0] + bv_);
        pk.y = f2bf(acc[mr][nc][1] + bv_);
        pk.z = f2bf(acc[mr][nc][2] + bv_);
        pk.w = f2bf(acc[mr][nc][3] + bv_);
        *(us4*)(vt + ((size_t)(bsel*HN+hh)*64 + dd)*NKL + nn) = pk;
      }
  }
}

// ---------------- GEMM1: out = aout(4096x1024 bf16) @ bto^T + bo, f32 out ----------------
// XCD swizzle: 512 blocks = 8 x 64.
__global__ __launch_bounds__(256) void gemm1_kernel(
    const u16* __restrict__ A, const u16* __restrict__ Bt,
    const float* __restrict__ bo, float* __restrict__ out)
{
  __shared__ u16 lds[(64+128)*64];   // A [64][64] @0, B [128][64] @8KB; 24 KB
  const int t = threadIdx.x;
  const int lane = t & 63, w = t >> 6;
  const int l15 = lane & 15, l4 = lane >> 4;
  const int lin = blockIdx.y*8 + blockIdx.x;      // [0,512)
  const int swz = (lin & 7)*64 + (lin >> 3);      // bijective: 512 = 8*64
  const int n0 = (swz & 7)*128, m0 = (swz >> 3)*64;
  const int wr = w >> 1, wc = w & 1;

  f32x4 acc[2][4];
  #pragma unroll
  for (int i=0;i<2;i++)
    #pragma unroll
    for (int j=0;j<4;j++){ acc[i][j][0]=0.f; acc[i][j][1]=0.f; acc[i][j][2]=0.f; acc[i][j][3]=0.f; }

  for (int kk=0; kk<16; kk++){
    #pragma unroll
    for (int i=0;i<2;i++){
      int o = i*4096 + w*1024 + lane*16;
      int row = o >> 7, c16 = (o >> 4) & 7;
      int c16s = c16 ^ (row & 7);
      gload16(A + ((size_t)(m0+row)*1024 + kk*64 + c16s*8), (char*)lds + (i*4096 + w*1024));
    }
    #pragma unroll
    for (int i=0;i<4;i++){
      int o = i*4096 + w*1024 + lane*16;
      int row = o >> 7, c16 = (o >> 4) & 7;
      int c16s = c16 ^ (row & 7);
      gload16(Bt + ((size_t)(n0+row)*1024 + kk*64 + c16s*8), (char*)lds + 8192 + (i*4096 + w*1024));
    }
    __syncthreads();

    short8 af[2][2], bf[4][2];
    #pragma unroll
    for (int mr=0;mr<2;mr++)
      #pragma unroll
      for (int ks=0;ks<2;ks++){
        int row = wr*32 + mr*16 + l15;
        int c16 = ks*4 + l4;
        af[mr][ks] = *(const short8*)((const char*)lds + row*128 + ((c16 ^ (row&7))*16));
      }
    #pragma unroll
    for (int nc=0;nc<4;nc++)
      #pragma unroll
      for (int ks=0;ks<2;ks++){
        int row = wc*64 + nc*16 + l15;
        int c16 = ks*4 + l4;
        bf[nc][ks] = *(const short8*)((const char*)lds + 8192 + row*128 + ((c16 ^ (row&7))*16));
      }
    #pragma unroll
    for (int ks=0;ks<2;ks++)
      #pragma unroll
      for (int mr=0;mr<2;mr++)
        #pragma unroll
        for (int nc=0;nc<4;nc++)
          acc[mr][nc] = MFMA16(af[mr][ks], bf[nc][ks], acc[mr][nc]);
    __syncthreads();
  }

  #pragma unroll
  for (int mr=0;mr<2;mr++)
    #pragma unroll
    for (int nc=0;nc<4;nc++)
      #pragma unroll
      for (int r=0;r<4;r++){
        int grow = m0 + wr*32 + mr*16 + l4*4 + r;
        int gcol = n0 + wc*64 + nc*16 + l15;
        out[(size_t)grow*1024 + gcol] = acc[mr][nc][r] + bo[gcol];
      }
}

// ---------------- flash attention v4 (R8-proven): 8-wave blocks, W LDS slab ----------------
__global__ __launch_bounds__(512) void attn_kernel(
  const u16* __restrict__ qp, const u16* __restrict__ kp, const u16* __restrict__ vt,
  const float* __restrict__ wts, u16* __restrict__ aout)
{
  __shared__ __align__(16) char lds[131072];
  char* kl = lds;
  char* vl = lds + 16384;
  const int tid = threadIdx.x;
  const int lane = tid & 63, wid = tid >> 6;
  const int lo = lane & 31, hi = lane >> 5;
  char* wl = lds + 32768 + wid*8192;
  char* pl = lds + 98304 + wid*4096;

  const int g = blockIdx.x;             // [0,256)
  const int j = g >> 3;                 // [0,32)
  const int bh = (g & 7)*4 + (j >> 3);  // 4 heads per XCD
  const int qblk = j & 7;               // 8 q-blocks of 256 rows
  const int b = bh >> 4;
  const int q0 = qblk*256 + wid*32;

  const u16* qb = qp + ((size_t)bh*NQL + q0)*64;
  const u16* kb = kp + (size_t)bh*NKL*64;
  const u16* vb = vt + (size_t)bh*64*NKL;
  const float* wb = wts + ((size_t)bh*NQL + q0)*(size_t)NKL;

  short8 qf[4];
  #pragma unroll
  for (int ks=0;ks<4;ks++)
    qf[ks] = *(const short8*)(qb + (size_t)lo*64 + ks*16 + hi*8);

  f32x16 o0, o1;
  float ls[16];
  #pragma unroll
  for (int r=0;r<16;r++){ o0[r]=0.f; o1[r]=0.f; ls[r]=0.f; }

  const int krow = tid >> 3, ksl = tid & 7;
  const int le16 = lane & 15, ld16 = lane >> 4;

  {
    gload16(kb + (size_t)krow*64 + (ksl ^ ((krow>>1)&7))*8, kl + tid*16);
    gload16(vb + (size_t)krow*NKL + (ksl ^ (krow&7))*8,     vl + tid*16);
    #pragma unroll
    for (int i=0;i<8;i++){
      int q = 4*i + ld16;
      gload16nt(wb + (size_t)q*NKL + le16*4, wl + i*1024);
    }
  }
  __syncthreads();

  for (int kt=0; kt<32; kt++){
    const int cur = (kt&1)*8192;
    const int nxt = cur ^ 8192;
    const int kb0 = kt*64;

    if (kt < 31){
      int kb1 = kb0 + 64;
      gload16(kb + (size_t)(kb1+krow)*64 + (ksl ^ ((krow>>1)&7))*8, kl + nxt + tid*16);
      gload16(vb + (size_t)krow*NKL + kb1 + (ksl ^ (krow&7))*8,     vl + nxt + tid*16);
    }

    f32x2 wp[16];
    #pragma unroll
    for (int r=0;r<16;r++){
      int qr = (r&3) + 8*(r>>2) + 4*hi;
      wp[r] = *(const f32x2*)(wl + qr*256 + lo*8);
    }
    short8 kf0[4], kf1[4];
    #pragma unroll
    for (int ks=0;ks<4;ks++){
      int slot = (ks*2 + hi) ^ (lo&7);
      kf0[ks] = *(const short8*)(kl + cur + (2*lo)*128 + slot*16);
      kf1[ks] = *(const short8*)(kl + cur + (2*lo)*128 + 128 + slot*16);
    }
    asm volatile("s_waitcnt lgkmcnt(0)" ::: "memory");
    __builtin_amdgcn_sched_barrier(0);

    if (kt < 31){
      int kb1 = kb0 + 64;
      #pragma unroll
      for (int i=0;i<8;i++){
        int q = 4*i + ld16;
        gload16nt(wb + (size_t)q*NKL + kb1 + le16*4, wl + i*1024);
      }
    }

    f32x16 s0, s1;
    #pragma unroll
    for (int r=0;r<16;r++){ s0[r]=0.f; s1[r]=0.f; }
    #pragma unroll
    for (int ks=0;ks<4;ks++){
      s0 = MFMA32(qf[ks], kf0[ks], s0);
      s1 = MFMA32(qf[ks], kf1[ks], s1);
    }

    short8 vf0[4], vf1[4];
    #pragma unroll
    for (int t=0;t<4;t++){
      int slot = (t*2 + hi) ^ (lo&7);
      vf0[t] = *(const short8*)(vl + cur + lo*128 + slot*16);
      vf1[t] = *(const short8*)(vl + cur + (32+lo)*128 + slot*16);
    }

    #pragma unroll
    for (int r=0;r<16;r++){
      float p0 = exp2f(s0[r] * wp[r].x);
      float p1 = exp2f(s1[r] * wp[r].y);
      ls[r] += p0 + p1;
      u32 pk;
      asm("v_cvt_pk_bf16_f32 %0, %1, %2" : "=v"(pk) : "v"(p0), "v"(p1));
      int row = (r&3) + 8*(r>>2) + 4*hi;
      *(u32*)(pl + row*128 + ((lo*4) ^ ((row&7)<<4))) = pk;
    }
    asm volatile("s_waitcnt lgkmcnt(0)" ::: "memory");
    short8 pf[4];
    #pragma unroll
    for (int t=0;t<4;t++)
      pf[t] = *(const short8*)(pl + lo*128 + ((t*32 + hi*16) ^ ((lo&7)<<4)));
    #pragma unroll
    for (int t=0;t<4;t++){
      o0 = MFMA32(pf[t], vf0[t], o0);
      o1 = MFMA32(pf[t], vf1[t], o1);
    }
    __syncthreads();
  }

  u16* ob = aout + ((size_t)b*NQL + q0)*DM + (bh & 15)*64;
  #pragma unroll
  for (int r=0;r<16;r++){
    float L = ls[r];
    L += __shfl_xor(L,1); L += __shfl_xor(L,2); L += __shfl_xor(L,4);
    L += __shfl_xor(L,8); L += __shfl_xor(L,16);
    float inv = 1.0f / L;
    int q = (r&3) + 8*(r>>2) + 4*hi;
    ob[(size_t)q*DM + lo]      = f2bf(o0[r]*inv);
    ob[(size_t)q*DM + 32 + lo] = f2bf(o1[r]*inv);
  }
}

// ---------------- launcher ----------------
extern "C" void kernel_launch(void* const* d_in, const int* in_sizes, int n_in,
                              void* d_out, int out_size, void* d_ws, size_t ws_size,
                              hipStream_t stream){
  const float* queries = (const float*)d_in[0];
  const float* keys    = (const float*)d_in[1];
  const float* values  = (const float*)d_in[2];
  const float* attw    = (const float*)d_in[3];
  const float* Wq = (const float*)d_in[4];
  const float* bq = (const float*)d_in[5];
  const float* Wk = (const float*)d_in[6];
  const float* bk = (const float*)d_in[7];
  const float* Wv = (const float*)d_in[8];
  const float* bv = (const float*)d_in[9];
  const float* Wo = (const float*)d_in[10];
  const float* bo = (const float*)d_in[11];
  char* ws = (char*)d_ws;
  u16* abf   = (u16*)(ws + OFF_ABF);
  u16* btqkv = (u16*)(ws + OFF_BTQKV);
  u16* bto   = (u16*)(ws + OFF_BTO);
  u16* qp    = (u16*)(ws + OFF_QP);
  u16* kp    = (u16*)(ws + OFF_KP);
  u16* vt    = (u16*)(ws + OFF_VT);
  u16* aout  = (u16*)(ws + OFF_AOUT);
  float* out = (float*)d_out;

  castw_kernel<<<16384, 256, 0, stream>>>(queries, keys, values, abf,
                                          Wq, Wk, Wv, Wo, btqkv, bto);
  gemm0_kernel<<<dim3(24,32), 256, 0, stream>>>(abf, btqkv, bq,bk,bv, qp,kp,vt);
  attn_kernel<<<256, 512, 0, stream>>>(qp, kp, vt, attw, aout);
  gemm1_kernel<<<dim3(8,64), 256, 0, stream>>>(aout, bto, bo, out);
}